// Round 10
// baseline (255.509 us; speedup 1.0000x reference)
//
#include <hip/hip_runtime.h>
#include <hip/hip_bf16.h>

// SegmentLinear: y = sum_c (sx_c*sw_c) * (qx_c @ qw_c^T), int8-exact path.
// N = K = O = 4096, CHUNKS = 4, cs = 1024.

constexpr int NDIM = 4096;
constexpr int TOTAL4 = (NDIM * NDIM) / 4;   // float4 count per matrix

typedef int i32x4 __attribute__((ext_vector_type(4)));

// ---------------------------------------------------------------- amax pass
__global__ __launch_bounds__(256) void amax_kernel(
    const float* __restrict__ x, const float* __restrict__ w,
    unsigned int* __restrict__ amax) {
  const int t = threadIdx.x;
  const int c = blockIdx.x & 3;  // grid stride (1024*256 float4) is a multiple
                                 // of K/4=1024 -> whole block stays in chunk c
  float mx = 0.f, mw = 0.f;
  const float4* x4 = (const float4*)x;
  const float4* w4 = (const float4*)w;
  const int stride = 1024 * 256;
  for (int i = blockIdx.x * 256 + t; i < TOTAL4; i += stride) {
    float4 v = x4[i];
    mx = fmaxf(mx, fmaxf(fmaxf(fabsf(v.x), fabsf(v.y)),
                         fmaxf(fabsf(v.z), fabsf(v.w))));
    float4 u = w4[i];
    mw = fmaxf(mw, fmaxf(fmaxf(fabsf(u.x), fabsf(u.y)),
                         fmaxf(fabsf(u.z), fabsf(u.w))));
  }
  __shared__ float r0[256], r1[256];
  r0[t] = mx; r1[t] = mw;
  __syncthreads();
  for (int off = 128; off; off >>= 1) {
    if (t < off) {
      r0[t] = fmaxf(r0[t], r0[t + off]);
      r1[t] = fmaxf(r1[t], r1[t + off]);
    }
    __syncthreads();
  }
  if (t == 0) {
    atomicMax(&amax[c],     __float_as_uint(r0[0]));  // non-neg: uint order == float order
    atomicMax(&amax[4 + c], __float_as_uint(r1[0]));
  }
}

// ------------------------------------------------------------- quantize pass
__device__ __forceinline__ signed char quant1(float v, float s) {
  float r = rintf(v / s);                       // round-half-even, IEEE div: matches numpy
  r = fminf(fmaxf(r, -127.f), 127.f);
  return (signed char)(int)r;
}

__global__ __launch_bounds__(256) void quant_kernel(
    const float* __restrict__ x, const float* __restrict__ w,
    const unsigned int* __restrict__ amax,
    signed char* __restrict__ qx, signed char* __restrict__ qw) {
  const int t = threadIdx.x;
  const int c = blockIdx.x & 3;
  const float sx = fmaxf(__uint_as_float(amax[c])     / 127.0f, 1e-8f);
  const float sw = fmaxf(__uint_as_float(amax[4 + c]) / 127.0f, 1e-8f);
  const float4* x4 = (const float4*)x;
  const float4* w4 = (const float4*)w;
  char4* qx4 = (char4*)qx;
  char4* qw4 = (char4*)qw;
  const int stride = 1024 * 256;
  for (int i = blockIdx.x * 256 + t; i < TOTAL4; i += stride) {
    float4 v = x4[i];
    char4 q;
    q.x = quant1(v.x, sx); q.y = quant1(v.y, sx);
    q.z = quant1(v.z, sx); q.w = quant1(v.w, sx);
    qx4[i] = q;
    float4 u = w4[i];
    char4 p;
    p.x = quant1(u.x, sw); p.y = quant1(u.y, sw);
    p.z = quant1(u.z, sw); p.w = quant1(u.w, sw);
    qw4[i] = p;
  }
}

// ------------------------------------------------------------------ i8 GEMM
__device__ __forceinline__ void async16(const void* g, void* l) {
  __builtin_amdgcn_global_load_lds(
      (const __attribute__((address_space(1))) void*)g,
      (__attribute__((address_space(3))) void*)l, 16, 0, 0);
}

// 128x128 tile, BK=128 int8 bytes, 4 waves (2x2), 64x64 out/wave.
// A: DIRECT global->VGPR per-wave loads (double-buffered reg sets, issued one
//    step ahead; wave = 16 rows x 64B contiguous per load -> 16 cache lines,
//    wave-pairs sharing wr hit L1 on identical addresses). No LDS for A.
// B: LDS via global_load_lds, 4 rotating 16 KB buffers (64 KB total).
// ONE barrier per K-step; counted vmcnt, sched_barrier-pinned FIFO:
//   per step t (buf p = t&3): issue order [A(t+1) 8][B-stage(t+2) 4]
//   entry queue = [B(t) 4, A(t) 8, B(t+1) 4]
//     vmcnt(4)  -> retires B(t)+A(t); B(t+1) stays in flight (never drain 0)
//     s_barrier -> all waves' B(t) visible; buf (t+2)&3 readers (step t-2)
//                  are all past BAR(t-1) -> re-stage race-free
//     issue A(t+1) -> reg set (t+1)&1 ; issue B-stage(t+2) -> buf (t+2)&3
//     COMPUTE: 8 ds_read_b128 (B frags) + 32 mfma_i32_16x16x64_i8 (setprio)
//     lgkmcnt(0)-> my B reads of buf p done (protects its re-stage at t+2)
// LDS/CU/step: 64 ds_read + 8 KB write ~ 830 cyc < MFMA 1306 cyc -> MFMA-bound.
// B swizzle (R7-proven, conflicts=0): 16B slot' = slot ^ (row&7), involution
// pre-applied to global source (linear gload_lds dest) and read address.
__global__ __launch_bounds__(256, 1) void gemm_i8_kernel(
    const signed char* __restrict__ qx, const signed char* __restrict__ qw,
    const unsigned int* __restrict__ amax, float* __restrict__ out) {
  __shared__ __align__(1024) signed char lds_b[4][16384];

  const int t = threadIdx.x;
  const int lane = t & 63;
  const int wave = t >> 6;
  const int brow = blockIdx.y * 128;   // plain 2D raster (proven L2 locality)
  const int bcol = blockIdx.x * 128;
  const int wr = wave >> 1;
  const int wc = wave & 1;

  // per-chunk combined scales -- computed and drained before any vm traffic.
  const float s0 = fmaxf(__uint_as_float(amax[0]) / 127.0f, 1e-8f) *
                   fmaxf(__uint_as_float(amax[4]) / 127.0f, 1e-8f);
  const float s1 = fmaxf(__uint_as_float(amax[1]) / 127.0f, 1e-8f) *
                   fmaxf(__uint_as_float(amax[5]) / 127.0f, 1e-8f);
  const float s2 = fmaxf(__uint_as_float(amax[2]) / 127.0f, 1e-8f) *
                   fmaxf(__uint_as_float(amax[6]) / 127.0f, 1e-8f);
  const float s3 = fmaxf(__uint_as_float(amax[3]) / 127.0f, 1e-8f) *
                   fmaxf(__uint_as_float(amax[7]) / 127.0f, 1e-8f);
  asm volatile("s_waitcnt vmcnt(0) lgkmcnt(0)" ::: "memory");
  __builtin_amdgcn_sched_barrier(0);

  // ---- B staging (R7 pattern): issue j=0..3 writes LDS [j*4096 + t*16]
  //   -> row = j*32 + (t>>3), slot = t&7. Global col pre-swizzled.
  const int srow = t >> 3;
  const int scol = (((t & 7) ^ (srow & 7)) << 4);
  const signed char* gB = qw + (size_t)(bcol + srow) * NDIM + scol;

  // ---- A direct-load base: lane row = wr*64 + l15, k-slot kg*16
  const int l15 = lane & 15;
  const int kg = lane >> 4;
  const signed char* gA = qx + (size_t)(brow + wr * 64 + l15) * NDIM + kg * 16;

  // ---- B fragment reads: row = wc*64 + n*16 + l15 (row&7 == lane&7)
  const int l7 = lane & 7;
  const int sk0 = ((kg) ^ l7) << 4;
  const int sk1 = ((4 + kg) ^ l7) << 4;
  const int rbb = (wc * 64 + l15) * 128;   // + n*2048

#define STAGE_B(BUF, T)                                               \
  do {                                                                \
    const size_t kt_ = (size_t)(T) * 128;                             \
    async16(gB + kt_,              &lds_b[BUF][0] + t * 16);          \
    async16(gB + kt_ + 32u * NDIM, &lds_b[BUF][4096] + t * 16);       \
    async16(gB + kt_ + 64u * NDIM, &lds_b[BUF][8192] + t * 16);       \
    async16(gB + kt_ + 96u * NDIM, &lds_b[BUF][12288] + t * 16);      \
  } while (0)

#define LOAD_A(SET, T)                                                \
  do {                                                                \
    const size_t kt_ = (size_t)(T) * 128;                             \
    _Pragma("unroll")                                                 \
    for (int m = 0; m < 4; ++m)                                       \
      _Pragma("unroll")                                               \
      for (int h = 0; h < 2; ++h)                                     \
        SET[m][h] = *(const i32x4*)(gA + kt_ +                        \
                                    (size_t)m * (16u * NDIM) + h * 64); \
  } while (0)

#define MM(AV, BV, M, N) \
  iacc[M][N] = __builtin_amdgcn_mfma_i32_16x16x64_i8((AV), (BV), iacc[M][N], 0, 0, 0)

#define SCB  __builtin_amdgcn_sched_barrier(0)
#define WAITV(N) \
  asm volatile("s_waitcnt vmcnt(" #N ")" ::: "memory"); SCB
#define WAITL \
  asm volatile("s_waitcnt lgkmcnt(0)" ::: "memory"); SCB
#define BAR \
  __builtin_amdgcn_s_barrier(); SCB

  i32x4 aA[4][2], aB[4][2];   // two A reg sets (all indices compile-time)
  i32x4 iacc[4][4];
  float facc[4][4][4];
#pragma unroll
  for (int m = 0; m < 4; ++m)
#pragma unroll
    for (int n = 0; n < 4; ++n) {
      iacc[m][n] = i32x4{0, 0, 0, 0};
#pragma unroll
      for (int j = 0; j < 4; ++j) facc[m][n][j] = 0.f;
    }

  // prologue: FIFO = [B0(4), A0(8), B1(4)] == steady entry shape
  STAGE_B(0, 0); SCB;
  LOAD_A(aA, 0); SCB;
  STAGE_B(1, 1); SCB;

#define COMPUTE(BUF, SET)                                               \
  do {                                                                  \
    i32x4 bv[4][2];                                                     \
    _Pragma("unroll")                                                   \
    for (int n = 0; n < 4; ++n) {                                       \
      bv[n][0] = *(const i32x4*)&lds_b[BUF][rbb + n * 2048 + sk0];      \
      bv[n][1] = *(const i32x4*)&lds_b[BUF][rbb + n * 2048 + sk1];      \
    }                                                                   \
    __builtin_amdgcn_s_setprio(1);                                      \
    _Pragma("unroll")                                                   \
    for (int h = 0; h < 2; ++h)                                         \
      _Pragma("unroll")                                                 \
      for (int m = 0; m < 4; ++m)                                       \
        _Pragma("unroll")                                               \
        for (int n = 0; n < 4; ++n)                                     \
          MM(SET[m][h], bv[n][h], m, n);                                \
    __builtin_amdgcn_s_setprio(0);                                      \
  } while (0)

#define FOLD(S)                                                         \
  do {                                                                  \
    _Pragma("unroll")                                                   \
    for (int m = 0; m < 4; ++m)                                         \
      _Pragma("unroll")                                                 \
      for (int n = 0; n < 4; ++n) {                                     \
        _Pragma("unroll")                                               \
        for (int j = 0; j < 4; ++j) facc[m][n][j] += (S) * (float)iacc[m][n][j]; \
        iacc[m][n] = i32x4{0, 0, 0, 0};                                 \
      }                                                                  \
  } while (0)

  // STEP(P, st): P = st&3 (compile-time), A set parity = st&1
#define STEP(P, ST, ASET, ANXT)                                         \
  do {                                                                  \
    WAITV(4);                                                           \
    BAR;                                                                \
    LOAD_A(ANXT, (ST) + 1); SCB;                                        \
    STAGE_B(((P) + 2) & 3, (ST) + 2); SCB;                              \
    COMPUTE(P, ASET);                                                   \
    WAITL;                                                              \
  } while (0)

  // steps 0..27 (k = 0..6); FOLD after steps 7, 15, 23
#pragma unroll 1
  for (int k = 0; k < 7; ++k) {
    const int st = k * 4;
    STEP(0, st + 0, aA, aB);
    STEP(1, st + 1, aB, aA);
    STEP(2, st + 2, aA, aB);
    STEP(3, st + 3, aB, aA);
    if (k == 1) FOLD(s0);
    else if (k == 3) FOLD(s1);
    else if (k == 5) FOLD(s2);
  }
  // step 28 (P0): normal
  STEP(0, 28, aA, aB);
  // step 29 (P1): normal (stages B31, loads A30)
  STEP(1, 29, aB, aA);
  // step 30 (P2): load A31, no B stage
  WAITV(4); BAR;
  LOAD_A(aB, 31); SCB;
  COMPUTE(2, aA);
  WAITL;
  // step 31 (P3): drain all, no issues
  WAITV(0); BAR;
  COMPUTE(3, aB);
  FOLD(s3);

  // C/D layout (16x16): col = lane&15, row = (lane>>4)*4 + j
  const int orow = brow + wr * 64 + (lane >> 4) * 4;
  const int ocol = bcol + wc * 64 + l15;
#pragma unroll
  for (int m = 0; m < 4; ++m)
#pragma unroll
    for (int n = 0; n < 4; ++n)
#pragma unroll
      for (int j = 0; j < 4; ++j)
        out[(size_t)(orow + m * 16 + j) * NDIM + (ocol + n * 16)] = facc[m][n][j];
#undef STAGE_B
#undef LOAD_A
#undef MM
#undef SCB
#undef WAITV
#undef WAITL
#undef BAR
#undef COMPUTE
#undef FOLD
#undef STEP
}

// ---------------------------------------------------------------- launcher
extern "C" void kernel_launch(void* const* d_in, const int* in_sizes, int n_in,
                              void* d_out, int out_size, void* d_ws, size_t ws_size,
                              hipStream_t stream) {
  const float* x = (const float*)d_in[0];
  const float* w = (const float*)d_in[1];
  float* out = (float*)d_out;

  unsigned int* amax = (unsigned int*)d_ws;                 // 8 uints
  signed char* qx = (signed char*)d_ws + 256;               // 16 MiB
  signed char* qw = qx + (size_t)NDIM * NDIM;               // 16 MiB

  hipMemsetAsync(d_ws, 0, 256, stream);
  amax_kernel<<<1024, 256, 0, stream>>>(x, w, amax);
  quant_kernel<<<1024, 256, 0, stream>>>(x, w, amax, qx, qw);
  dim3 grid(NDIM / 128, NDIM / 128);
  gemm_i8_kernel<<<grid, 256, 0, stream>>>(qx, qw, amax, out);
}

// Round 11
// 193.540 us; speedup vs baseline: 1.3202x; 1.3202x over previous
//
#include <hip/hip_runtime.h>
#include <hip/hip_bf16.h>

// SegmentLinear: y = sum_c (sx_c*sw_c) * (qx_c @ qw_c^T), int8-exact path.
// N = K = O = 4096, CHUNKS = 4, cs = 1024.

constexpr int NDIM = 4096;
constexpr int TOTAL4 = (NDIM * NDIM) / 4;   // float4 count per matrix

typedef int i32x4 __attribute__((ext_vector_type(4)));

// ---------------------------------------------------------------- amax pass
__global__ __launch_bounds__(256) void amax_kernel(
    const float* __restrict__ x, const float* __restrict__ w,
    unsigned int* __restrict__ amax) {
  const int t = threadIdx.x;
  const int c = blockIdx.x & 3;  // grid stride (1024*256 float4) is a multiple
                                 // of K/4=1024 -> whole block stays in chunk c
  float mx = 0.f, mw = 0.f;
  const float4* x4 = (const float4*)x;
  const float4* w4 = (const float4*)w;
  const int stride = 1024 * 256;
  for (int i = blockIdx.x * 256 + t; i < TOTAL4; i += stride) {
    float4 v = x4[i];
    mx = fmaxf(mx, fmaxf(fmaxf(fabsf(v.x), fabsf(v.y)),
                         fmaxf(fabsf(v.z), fabsf(v.w))));
    float4 u = w4[i];
    mw = fmaxf(mw, fmaxf(fmaxf(fabsf(u.x), fabsf(u.y)),
                         fmaxf(fabsf(u.z), fabsf(u.w))));
  }
  __shared__ float r0[256], r1[256];
  r0[t] = mx; r1[t] = mw;
  __syncthreads();
  for (int off = 128; off; off >>= 1) {
    if (t < off) {
      r0[t] = fmaxf(r0[t], r0[t + off]);
      r1[t] = fmaxf(r1[t], r1[t + off]);
    }
    __syncthreads();
  }
  if (t == 0) {
    atomicMax(&amax[c],     __float_as_uint(r0[0]));  // non-neg: uint order == float order
    atomicMax(&amax[4 + c], __float_as_uint(r1[0]));
  }
}

// ------------------------------------------------------------- quantize pass
__device__ __forceinline__ signed char quant1(float v, float s) {
  float r = rintf(v / s);                       // round-half-even, IEEE div: matches numpy
  r = fminf(fmaxf(r, -127.f), 127.f);
  return (signed char)(int)r;
}

__global__ __launch_bounds__(256) void quant_kernel(
    const float* __restrict__ x, const float* __restrict__ w,
    const unsigned int* __restrict__ amax,
    signed char* __restrict__ qx, signed char* __restrict__ qw) {
  const int t = threadIdx.x;
  const int c = blockIdx.x & 3;
  const float sx = fmaxf(__uint_as_float(amax[c])     / 127.0f, 1e-8f);
  const float sw = fmaxf(__uint_as_float(amax[4 + c]) / 127.0f, 1e-8f);
  const float4* x4 = (const float4*)x;
  const float4* w4 = (const float4*)w;
  char4* qx4 = (char4*)qx;
  char4* qw4 = (char4*)qw;
  const int stride = 1024 * 256;
  for (int i = blockIdx.x * 256 + t; i < TOTAL4; i += stride) {
    float4 v = x4[i];
    char4 q;
    q.x = quant1(v.x, sx); q.y = quant1(v.y, sx);
    q.z = quant1(v.z, sx); q.w = quant1(v.w, sx);
    qx4[i] = q;
    float4 u = w4[i];
    char4 p;
    p.x = quant1(u.x, sw); p.y = quant1(u.y, sw);
    p.z = quant1(u.z, sw); p.w = quant1(u.w, sw);
    qw4[i] = p;
  }
}

// ------------------------------------------------------------------ i8 GEMM
__device__ __forceinline__ void async16(const void* g, void* l) {
  __builtin_amdgcn_global_load_lds(
      (const __attribute__((address_space(1))) void*)g,
      (__attribute__((address_space(3))) void*)l, 16, 0, 0);
}

// 128x128 tile, BK=128 int8 bytes, 4 waves (2x2), 64x64 out/wave, 2 buffers
// (64 KB LDS, 2 blocks/CU). m201-style PHASE-SPLIT K-step: each step t
// (buf p = t&1) runs two phases, one per 64B k-half:
//   phase h: { 8 ds_read (4 av + 4 bv of half h)   <- issued into barrier slack
//              4-load stage of half h of tile t+1 -> buf p^1
//              BAR; lgkmcnt(0); setprio1; 16 MFMA cluster; setprio0; BAR }
// Step end: vmcnt(0) (stage issued ~1.5 phases earlier -> L2 latency covered)
// then BAR -> buf p^1 visible for step t+1. Race ledger: STAGE into p^1 at
// phase A issues after step t-1's final BAR, by which point every wave's
// reads of p^1 (step t-1, protected by its own WAITL before that BAR) are
// retired. 4 barriers/step, 16 MFMA per cluster, 2 blocks/CU (vs R9's
// failed 8-MFMA phases at 1 block/CU).
// Swizzle (R7-proven, conflicts=0): 16B slot' = slot ^ (row&7), involution
// pre-applied to global source (linear gload_lds dest) and read address.
__global__ __launch_bounds__(256, 2) void gemm_i8_kernel(
    const signed char* __restrict__ qx, const signed char* __restrict__ qw,
    const unsigned int* __restrict__ amax, float* __restrict__ out) {
  __shared__ __align__(1024) signed char lds_a[2][16384];
  __shared__ __align__(1024) signed char lds_b[2][16384];

  const int t = threadIdx.x;
  const int lane = t & 63;
  const int wave = t >> 6;
  const int brow = blockIdx.y * 128;   // plain 2D raster (proven L2 locality)
  const int bcol = blockIdx.x * 128;
  const int wr = wave >> 1;
  const int wc = wave & 1;

  // per-chunk combined scales -- computed and drained before any vm traffic.
  const float s0 = fmaxf(__uint_as_float(amax[0]) / 127.0f, 1e-8f) *
                   fmaxf(__uint_as_float(amax[4]) / 127.0f, 1e-8f);
  const float s1 = fmaxf(__uint_as_float(amax[1]) / 127.0f, 1e-8f) *
                   fmaxf(__uint_as_float(amax[5]) / 127.0f, 1e-8f);
  const float s2 = fmaxf(__uint_as_float(amax[2]) / 127.0f, 1e-8f) *
                   fmaxf(__uint_as_float(amax[6]) / 127.0f, 1e-8f);
  const float s3 = fmaxf(__uint_as_float(amax[3]) / 127.0f, 1e-8f) *
                   fmaxf(__uint_as_float(amax[7]) / 127.0f, 1e-8f);
  asm volatile("s_waitcnt vmcnt(0) lgkmcnt(0)" ::: "memory");
  __builtin_amdgcn_sched_barrier(0);

  // staging (R7 pattern): issue j (j=0..3 per matrix) writes LDS
  // [j*4096 + t*16] -> row = j*32 + (t>>3), slot = t&7 (linear dest).
  // Global col pre-swizzled: (t&7) ^ ((t>>3)&7) == slot ^ (row&7) for all j.
  const int srow = t >> 3;
  const int scol = (((t & 7) ^ (srow & 7)) << 4);
  const signed char* gA = qx + (size_t)(brow + srow) * NDIM + scol;
  const signed char* gB = qw + (size_t)(bcol + srow) * NDIM + scol;

  // fragment reads: row = wtile + {m,n}*16 + (lane&15); row&7 == lane&7.
  // k byte-slot for half h, group kg: slot = (h*4+kg) ^ (lane&7).
  const int l15 = lane & 15;
  const int kg = lane >> 4;
  const int l7 = lane & 7;
  const int sk0 = ((kg) ^ l7) << 4;
  const int sk1 = ((4 + kg) ^ l7) << 4;
  const int rba = (wr * 64 + l15) * 128;   // + m*2048
  const int rbb = (wc * 64 + l15) * 128;   // + n*2048

#define STAGE_A(BUF, T)                                               \
  do {                                                                \
    const size_t kt_ = (size_t)(T) * 128;                             \
    async16(gA + kt_,              &lds_a[BUF][0] + t * 16);          \
    async16(gA + kt_ + 32u * NDIM, &lds_a[BUF][4096] + t * 16);       \
    async16(gA + kt_ + 64u * NDIM, &lds_a[BUF][8192] + t * 16);      \
    async16(gA + kt_ + 96u * NDIM, &lds_a[BUF][12288] + t * 16);      \
  } while (0)
#define STAGE_B(BUF, T)                                               \
  do {                                                                \
    const size_t kt_ = (size_t)(T) * 128;                             \
    async16(gB + kt_,              &lds_b[BUF][0] + t * 16);          \
    async16(gB + kt_ + 32u * NDIM, &lds_b[BUF][4096] + t * 16);       \
    async16(gB + kt_ + 64u * NDIM, &lds_b[BUF][8192] + t * 16);      \
    async16(gB + kt_ + 96u * NDIM, &lds_b[BUF][12288] + t * 16);      \
  } while (0)

#define RD_A(P, M, SK) (*(const i32x4*)&lds_a[P][rba + (M) * 2048 + (SK)])
#define RD_B(P, N, SK) (*(const i32x4*)&lds_b[P][rbb + (N) * 2048 + (SK)])
#define MM(AV, BV, M, N) \
  iacc[M][N] = __builtin_amdgcn_mfma_i32_16x16x64_i8((AV), (BV), iacc[M][N], 0, 0, 0)

#define SCB  __builtin_amdgcn_sched_barrier(0)
#define WAITL \
  asm volatile("s_waitcnt lgkmcnt(0)" ::: "memory"); SCB
#define BAR \
  __builtin_amdgcn_s_barrier(); SCB

  i32x4 iacc[4][4];
  float facc[4][4][4];
#pragma unroll
  for (int m = 0; m < 4; ++m)
#pragma unroll
    for (int n = 0; n < 4; ++n) {
      iacc[m][n] = i32x4{0, 0, 0, 0};
#pragma unroll
      for (int j = 0; j < 4; ++j) facc[m][n][j] = 0.f;
    }

  // prologue: stage tile 0 into buf 0, drain, sync
  STAGE_A(0, 0); STAGE_B(0, 0);
  asm volatile("s_waitcnt vmcnt(0)" ::: "memory"); SCB;
  BAR;

#define MFMA16(A0, A1, A2, A3, B0, B1, B2, B3)                          \
  do {                                                                  \
    __builtin_amdgcn_s_setprio(1);                                      \
    MM(A0, B0, 0, 0); MM(A1, B0, 1, 0); MM(A2, B0, 2, 0); MM(A3, B0, 3, 0); \
    MM(A0, B1, 0, 1); MM(A1, B1, 1, 1); MM(A2, B1, 2, 1); MM(A3, B1, 3, 1); \
    MM(A0, B2, 0, 2); MM(A1, B2, 1, 2); MM(A2, B2, 2, 2); MM(A3, B2, 3, 2); \
    MM(A0, B3, 0, 3); MM(A1, B3, 1, 3); MM(A2, B3, 2, 3); MM(A3, B3, 3, 3); \
    __builtin_amdgcn_s_setprio(0);                                      \
  } while (0)

  // STEP: P = buf (compile-time), stages tile T+1 into P^1 when EN
#define STEP(P, T, EN, VM)                                              \
  do {                                                                  \
    { /* phase A: k-half 0 */                                           \
      i32x4 a0 = RD_A(P, 0, sk0), a1 = RD_A(P, 1, sk0);                 \
      i32x4 a2 = RD_A(P, 2, sk0), a3 = RD_A(P, 3, sk0);                 \
      i32x4 b0 = RD_B(P, 0, sk0), b1 = RD_B(P, 1, sk0);                 \
      i32x4 b2 = RD_B(P, 2, sk0), b3 = RD_B(P, 3, sk0);                 \
      if (EN) STAGE_A((P) ^ 1, (T) + 1);                                \
      SCB;                                                              \
      BAR; WAITL;                                                       \
      MFMA16(a0, a1, a2, a3, b0, b1, b2, b3);                           \
      BAR;                                                              \
    }                                                                   \
    { /* phase B: k-half 1 */                                           \
      i32x4 a0 = RD_A(P, 0, sk1), a1 = RD_A(P, 1, sk1);                 \
      i32x4 a2 = RD_A(P, 2, sk1), a3 = RD_A(P, 3, sk1);                 \
      i32x4 b0 = RD_B(P, 0, sk1), b1 = RD_B(P, 1, sk1);                 \
      i32x4 b2 = RD_B(P, 2, sk1), b3 = RD_B(P, 3, sk1);                 \
      if (EN) STAGE_B((P) ^ 1, (T) + 1);                                \
      SCB;                                                              \
      BAR; WAITL;                                                       \
      MFMA16(a0, a1, a2, a3, b0, b1, b2, b3);                           \
      asm volatile(VM ::: "memory"); SCB;                               \
      BAR;                                                              \
    }                                                                   \
  } while (0)

#define FOLD(S)                                                         \
  do {                                                                  \
    _Pragma("unroll")                                                   \
    for (int m = 0; m < 4; ++m)                                         \
      _Pragma("unroll")                                                 \
      for (int n = 0; n < 4; ++n) {                                     \
        _Pragma("unroll")                                               \
        for (int j = 0; j < 4; ++j) facc[m][n][j] += (S) * (float)iacc[m][n][j]; \
        iacc[m][n] = i32x4{0, 0, 0, 0};                                 \
      }                                                                  \
  } while (0)

  // 32 K-tiles of 128 B; chunk c = tiles 8c..8c+7; folds after 7,15,23,31.
#pragma unroll 1
  for (int it = 0; it < 15; ++it) {     // steps 0..29
    STEP(0, 2 * it, 1, "s_waitcnt vmcnt(0)");
    STEP(1, 2 * it + 1, 1, "s_waitcnt vmcnt(0)");
    if (it == 3) FOLD(s0);
    else if (it == 7) FOLD(s1);
    else if (it == 11) FOLD(s2);
  }
  STEP(0, 30, 1, "s_waitcnt vmcnt(0)");  // step 30, stages tile 31
  STEP(1, 31, 0, "s_nop 0");             // step 31, nothing in flight
  FOLD(s3);

  // C/D layout (16x16): col = lane&15, row = (lane>>4)*4 + j
  const int orow = brow + wr * 64 + (lane >> 4) * 4;
  const int ocol = bcol + wc * 64 + l15;
#pragma unroll
  for (int m = 0; m < 4; ++m)
#pragma unroll
    for (int n = 0; n < 4; ++n)
#pragma unroll
      for (int j = 0; j < 4; ++j)
        out[(size_t)(orow + m * 16 + j) * NDIM + (ocol + n * 16)] = facc[m][n][j];
#undef STAGE_A
#undef STAGE_B
#undef RD_A
#undef RD_B
#undef MM
#undef SCB
#undef WAITL
#undef BAR
#undef MFMA16
#undef STEP
#undef FOLD
}

// ---------------------------------------------------------------- launcher
extern "C" void kernel_launch(void* const* d_in, const int* in_sizes, int n_in,
                              void* d_out, int out_size, void* d_ws, size_t ws_size,
                              hipStream_t stream) {
  const float* x = (const float*)d_in[0];
  const float* w = (const float*)d_in[1];
  float* out = (float*)d_out;

  unsigned int* amax = (unsigned int*)d_ws;                 // 8 uints
  signed char* qx = (signed char*)d_ws + 256;               // 16 MiB
  signed char* qw = qx + (size_t)NDIM * NDIM;               // 16 MiB

  hipMemsetAsync(d_ws, 0, 256, stream);
  amax_kernel<<<1024, 256, 0, stream>>>(x, w, amax);
  quant_kernel<<<1024, 256, 0, stream>>>(x, w, amax, qx, qw);
  dim3 grid(NDIM / 128, NDIM / 128);
  gemm_i8_kernel<<<grid, 256, 0, stream>>>(qx, qw, amax, out);
}

// Round 12
// 154.705 us; speedup vs baseline: 1.6516x; 1.2510x over previous
//
#include <hip/hip_runtime.h>
#include <hip/hip_bf16.h>

// SegmentLinear: y = sum_c (sx_c*sw_c) * (qx_c @ qw_c^T), int8-exact path.
// N = K = O = 4096, CHUNKS = 4, cs = 1024.

constexpr int NDIM = 4096;
constexpr int TOTAL4 = (NDIM * NDIM) / 4;   // float4 count per matrix

typedef int i32x4 __attribute__((ext_vector_type(4)));

// ---------------------------------------------------------------- amax pass
__global__ __launch_bounds__(256) void amax_kernel(
    const float* __restrict__ x, const float* __restrict__ w,
    unsigned int* __restrict__ amax) {
  const int t = threadIdx.x;
  const int c = blockIdx.x & 3;  // grid stride (1024*256 float4) is a multiple
                                 // of K/4=1024 -> whole block stays in chunk c
  float mx = 0.f, mw = 0.f;
  const float4* x4 = (const float4*)x;
  const float4* w4 = (const float4*)w;
  const int stride = 1024 * 256;
  for (int i = blockIdx.x * 256 + t; i < TOTAL4; i += stride) {
    float4 v = x4[i];
    mx = fmaxf(mx, fmaxf(fmaxf(fabsf(v.x), fabsf(v.y)),
                         fmaxf(fabsf(v.z), fabsf(v.w))));
    float4 u = w4[i];
    mw = fmaxf(mw, fmaxf(fmaxf(fabsf(u.x), fabsf(u.y)),
                         fmaxf(fabsf(u.z), fabsf(u.w))));
  }
  __shared__ float r0[256], r1[256];
  r0[t] = mx; r1[t] = mw;
  __syncthreads();
  for (int off = 128; off; off >>= 1) {
    if (t < off) {
      r0[t] = fmaxf(r0[t], r0[t + off]);
      r1[t] = fmaxf(r1[t], r1[t + off]);
    }
    __syncthreads();
  }
  if (t == 0) {
    atomicMax(&amax[c],     __float_as_uint(r0[0]));  // non-neg: uint order == float order
    atomicMax(&amax[4 + c], __float_as_uint(r1[0]));
  }
}

// ------------------------------------------------------------- quantize pass
__device__ __forceinline__ signed char quant1(float v, float s) {
  float r = rintf(v / s);                       // round-half-even, IEEE div: matches numpy
  r = fminf(fmaxf(r, -127.f), 127.f);
  return (signed char)(int)r;
}

__global__ __launch_bounds__(256) void quant_kernel(
    const float* __restrict__ x, const float* __restrict__ w,
    const unsigned int* __restrict__ amax,
    signed char* __restrict__ qx, signed char* __restrict__ qw) {
  const int t = threadIdx.x;
  const int c = blockIdx.x & 3;
  const float sx = fmaxf(__uint_as_float(amax[c])     / 127.0f, 1e-8f);
  const float sw = fmaxf(__uint_as_float(amax[4 + c]) / 127.0f, 1e-8f);
  const float4* x4 = (const float4*)x;
  const float4* w4 = (const float4*)w;
  char4* qx4 = (char4*)qx;
  char4* qw4 = (char4*)qw;
  const int stride = 1024 * 256;
  for (int i = blockIdx.x * 256 + t; i < TOTAL4; i += stride) {
    float4 v = x4[i];
    char4 q;
    q.x = quant1(v.x, sx); q.y = quant1(v.y, sx);
    q.z = quant1(v.z, sx); q.w = quant1(v.w, sx);
    qx4[i] = q;
    float4 u = w4[i];
    char4 p;
    p.x = quant1(u.x, sw); p.y = quant1(u.y, sw);
    p.z = quant1(u.z, sw); p.w = quant1(u.w, sw);
    qw4[i] = p;
  }
}

// ------------------------------------------------------------------ i8 GEMM
__device__ __forceinline__ void async16(const void* g, void* l) {
  __builtin_amdgcn_global_load_lds(
      (const __attribute__((address_space(1))) void*)g,
      (__attribute__((address_space(3))) void*)l, 16, 0, 0);
}

// 256x128 tile, BK=128 int8 bytes, 512 threads = 8 waves (4x2), 64x64/wave.
// __launch_bounds__(512,1): VGPR cap 256 (working set ~190: 16 frags + iacc
// 64 + facc 64 + addr) -> NO spill (R11's cap-128 spill fixed); 8 waves =
// 2/SIMD, 1 block/CU. LDS: THREE rotating 48 KB buffers (A 32 KB + B 16 KB)
// = 144 KB <= 160 KB pool -> depth-3 pipeline with COUNTED end-of-step
// vmcnt(6) (tile t+2's 6 loads stay in flight; ~2 steps latency cover).
// Per step t (buf p = t%3, compile-time via 3x unroll), 2 phases:
//   phase h: { 8 ds_read (4 av + 4 bv, k-half h)   <- issued into barrier slack
//              stage part of tile t+2 -> buf (t+2)%3 (A:4 loads / B:2 loads)
//              BAR; lgkmcnt(0); setprio1; 16-MFMA cluster; setprio0; BAR }
//   step end (phase B): s_waitcnt vmcnt(6) -> tile t+1 resident; BAR.
// Race ledger: stage into (t+2)%3 == (t-1)%3 issues after step t-1's final
// BAR, by which point every wave's reads of that buf (drained by its WAITL
// before that BAR) are retired. Staged data visibility: end-of-step vmcnt(6)
// + BAR makes tile t+1 visible before step t+1's phase-A ds_reads.
// Swizzle (R7-proven, conflicts=0): 16B slot' = slot ^ (row&7), involution
// pre-applied to global source (linear gload_lds dest) and read address.
__global__ __launch_bounds__(512, 1) void gemm_i8_kernel(
    const signed char* __restrict__ qx, const signed char* __restrict__ qw,
    const unsigned int* __restrict__ amax, float* __restrict__ out) {
  __shared__ __align__(1024) signed char lds_a[3][32768];
  __shared__ __align__(1024) signed char lds_b[3][16384];

  const int t = threadIdx.x;          // 0..511
  const int lane = t & 63;
  const int wave = t >> 6;            // 0..7
  const int brow = blockIdx.y * 256;  // plain 2D raster
  const int bcol = blockIdx.x * 128;
  const int wr = wave >> 1;           // 0..3 (m, 64 rows each)
  const int wc = wave & 1;            // 0..1 (n, 64 cols each)

  // per-chunk combined scales -- computed and drained before any vm traffic.
  const float s0 = fmaxf(__uint_as_float(amax[0]) / 127.0f, 1e-8f) *
                   fmaxf(__uint_as_float(amax[4]) / 127.0f, 1e-8f);
  const float s1 = fmaxf(__uint_as_float(amax[1]) / 127.0f, 1e-8f) *
                   fmaxf(__uint_as_float(amax[5]) / 127.0f, 1e-8f);
  const float s2 = fmaxf(__uint_as_float(amax[2]) / 127.0f, 1e-8f) *
                   fmaxf(__uint_as_float(amax[6]) / 127.0f, 1e-8f);
  const float s3 = fmaxf(__uint_as_float(amax[3]) / 127.0f, 1e-8f) *
                   fmaxf(__uint_as_float(amax[7]) / 127.0f, 1e-8f);
  asm volatile("s_waitcnt vmcnt(0) lgkmcnt(0)" ::: "memory");
  __builtin_amdgcn_sched_barrier(0);

  // staging: A issue j (0..3) writes LDS [j*8192 + t*16] -> row j*64+(t>>3),
  // slot t&7; B issue j (0,1) same with 64-row issues. Global col
  // pre-swizzled: (t&7) ^ ((t>>3)&7) == slot ^ (row&7) (j*64 == 0 mod 8).
  const int srow = t >> 3;                               // 0..63
  const int scol = (((t & 7) ^ (srow & 7)) << 4);
  const signed char* gA = qx + (size_t)(brow + srow) * NDIM + scol;
  const signed char* gB = qw + (size_t)(bcol + srow) * NDIM + scol;

  // fragment reads: row = wtile + {m,n}*16 + (lane&15); row&7 == lane&7.
  const int l15 = lane & 15;
  const int kg = lane >> 4;
  const int l7 = lane & 7;
  const int sk0 = ((kg) ^ l7) << 4;
  const int sk1 = ((4 + kg) ^ l7) << 4;
  const int rba = (wr * 64 + l15) * 128;   // + m*2048 (within 32 KB)
  const int rbb = (wc * 64 + l15) * 128;   // + n*2048 (within 16 KB)

#define STAGE_A(P, T)                                                 \
  do {                                                                \
    const size_t kt_ = (size_t)(T) * 128;                             \
    async16(gA + kt_,               &lds_a[P][0] + t * 16);           \
    async16(gA + kt_ + 64u * NDIM,  &lds_a[P][8192] + t * 16);        \
    async16(gA + kt_ + 128u * NDIM, &lds_a[P][16384] + t * 16);       \
    async16(gA + kt_ + 192u * NDIM, &lds_a[P][24576] + t * 16);       \
  } while (0)
#define STAGE_B(P, T)                                                 \
  do {                                                                \
    const size_t kt_ = (size_t)(T) * 128;                             \
    async16(gB + kt_,              &lds_b[P][0] + t * 16);            \
    async16(gB + kt_ + 64u * NDIM, &lds_b[P][8192] + t * 16);         \
  } while (0)

#define RD_A(P, M, SK) (*(const i32x4*)&lds_a[P][rba + (M) * 2048 + (SK)])
#define RD_B(P, N, SK) (*(const i32x4*)&lds_b[P][rbb + (N) * 2048 + (SK)])
#define MM(AV, BV, M, N) \
  iacc[M][N] = __builtin_amdgcn_mfma_i32_16x16x64_i8((AV), (BV), iacc[M][N], 0, 0, 0)

#define SCB  __builtin_amdgcn_sched_barrier(0)
#define WAITL \
  asm volatile("s_waitcnt lgkmcnt(0)" ::: "memory"); SCB
#define BAR \
  __builtin_amdgcn_s_barrier(); SCB

  i32x4 iacc[4][4];
  float facc[4][4][4];
#pragma unroll
  for (int m = 0; m < 4; ++m)
#pragma unroll
    for (int n = 0; n < 4; ++n) {
      iacc[m][n] = i32x4{0, 0, 0, 0};
#pragma unroll
      for (int j = 0; j < 4; ++j) facc[m][n][j] = 0.f;
    }

  // prologue: tiles 0,1 staged (12 loads); tile 0 resident before loop.
  STAGE_A(0, 0); STAGE_B(0, 0);
  STAGE_A(1, 1); STAGE_B(1, 1);
  asm volatile("s_waitcnt vmcnt(6)" ::: "memory"); SCB;
  BAR;

#define MFMA16(A0, A1, A2, A3, B0, B1, B2, B3)                          \
  do {                                                                  \
    __builtin_amdgcn_s_setprio(1);                                      \
    MM(A0, B0, 0, 0); MM(A1, B0, 1, 0); MM(A2, B0, 2, 0); MM(A3, B0, 3, 0); \
    MM(A0, B1, 0, 1); MM(A1, B1, 1, 1); MM(A2, B1, 2, 1); MM(A3, B1, 3, 1); \
    MM(A0, B2, 0, 2); MM(A1, B2, 1, 2); MM(A2, B2, 2, 2); MM(A3, B2, 3, 2); \
    MM(A0, B3, 0, 3); MM(A1, B3, 1, 3); MM(A2, B3, 2, 3); MM(A3, B3, 3, 3); \
    __builtin_amdgcn_s_setprio(0);                                      \
  } while (0)

  // STEP: P = buf (compile-time), P2 = (P+2)%3; stages tile T+2 when EN.
#define STEP(P, P2, T, EN, VM)                                          \
  do {                                                                  \
    { /* phase A: k-half 0 */                                           \
      i32x4 a0 = RD_A(P, 0, sk0), a1 = RD_A(P, 1, sk0);                 \
      i32x4 a2 = RD_A(P, 2, sk0), a3 = RD_A(P, 3, sk0);                 \
      i32x4 b0 = RD_B(P, 0, sk0), b1 = RD_B(P, 1, sk0);                 \
      i32x4 b2 = RD_B(P, 2, sk0), b3 = RD_B(P, 3, sk0);                 \
      if (EN) STAGE_A(P2, (T) + 2);                                     \
      SCB;                                                              \
      BAR; WAITL;                                                       \
      MFMA16(a0, a1, a2, a3, b0, b1, b2, b3);                           \
      BAR;                                                              \
    }                                                                   \
    { /* phase B: k-half 1 */                                           \
      i32x4 a0 = RD_A(P, 0, sk1), a1 = RD_A(P, 1, sk1);                 \
      i32x4 a2 = RD_A(P, 2, sk1), a3 = RD_A(P, 3, sk1);                 \
      i32x4 b0 = RD_B(P, 0, sk1), b1 = RD_B(P, 1, sk1);                 \
      i32x4 b2 = RD_B(P, 2, sk1), b3 = RD_B(P, 3, sk1);                 \
      if (EN) STAGE_B(P2, (T) + 2);                                     \
      SCB;                                                              \
      BAR; WAITL;                                                       \
      MFMA16(a0, a1, a2, a3, b0, b1, b2, b3);                           \
      asm volatile(VM ::: "memory"); SCB;                               \
      BAR;                                                              \
    }                                                                   \
  } while (0)

#define FOLD(S)                                                         \
  do {                                                                  \
    _Pragma("unroll")                                                   \
    for (int m = 0; m < 4; ++m)                                         \
      _Pragma("unroll")                                                 \
      for (int n = 0; n < 4; ++n) {                                     \
        _Pragma("unroll")                                               \
        for (int j = 0; j < 4; ++j) facc[m][n][j] += (S) * (float)iacc[m][n][j]; \
        iacc[m][n] = i32x4{0, 0, 0, 0};                                 \
      }                                                                  \
  } while (0)

#define FOLDCHK(ST)                                                     \
  do {                                                                  \
    if (((ST) & 7) == 7 && (ST) < 31) {                                 \
      const int ci = (ST) >> 3;                                         \
      FOLD(ci == 0 ? s0 : ci == 1 ? s1 : s2);                           \
    }                                                                   \
  } while (0)

  // 32 K-tiles of 128 B; chunk c = tiles 8c..8c+7; folds after 7,15,23,31.
#pragma unroll 1
  for (int b3 = 0; b3 < 10; ++b3) {    // steps 0..29
    const int st = b3 * 3;
    STEP(0, 2, st + 0, 1, "s_waitcnt vmcnt(6)");
    FOLDCHK(st + 0);
    STEP(1, 0, st + 1, 1, "s_waitcnt vmcnt(6)");
    FOLDCHK(st + 1);
    STEP(2, 1, st + 2, 1, "s_waitcnt vmcnt(6)");
    FOLDCHK(st + 2);
  }
  // step 30 (buf 0): no stage; drain tile 31's 6 loads
  STEP(0, 2, 30, 0, "s_waitcnt vmcnt(0)");
  // step 31 (buf 1): nothing in flight
  STEP(1, 0, 31, 0, "s_nop 0");
  FOLD(s3);

  // C/D layout (16x16): col = lane&15, row = (lane>>4)*4 + j
  const int orow = brow + wr * 64 + (lane >> 4) * 4;
  const int ocol = bcol + wc * 64 + l15;
#pragma unroll
  for (int m = 0; m < 4; ++m)
#pragma unroll
    for (int n = 0; n < 4; ++n)
#pragma unroll
      for (int j = 0; j < 4; ++j)
        out[(size_t)(orow + m * 16 + j) * NDIM + (ocol + n * 16)] = facc[m][n][j];
#undef STAGE_A
#undef STAGE_B
#undef RD_A
#undef RD_B
#undef MM
#undef SCB
#undef WAITL
#undef BAR
#undef MFMA16
#undef STEP
#undef FOLD
#undef FOLDCHK
}

// ---------------------------------------------------------------- launcher
extern "C" void kernel_launch(void* const* d_in, const int* in_sizes, int n_in,
                              void* d_out, int out_size, void* d_ws, size_t ws_size,
                              hipStream_t stream) {
  const float* x = (const float*)d_in[0];
  const float* w = (const float*)d_in[1];
  float* out = (float*)d_out;

  unsigned int* amax = (unsigned int*)d_ws;                 // 8 uints
  signed char* qx = (signed char*)d_ws + 256;               // 16 MiB
  signed char* qw = qx + (size_t)NDIM * NDIM;               // 16 MiB

  hipMemsetAsync(d_ws, 0, 256, stream);
  amax_kernel<<<1024, 256, 0, stream>>>(x, w, amax);
  quant_kernel<<<1024, 256, 0, stream>>>(x, w, amax, qx, qw);
  dim3 grid(NDIM / 128, NDIM / 256);   // 32 col-tiles x 16 row-tiles
  gemm_i8_kernel<<<grid, 512, 0, stream>>>(qx, qw, amax, out);
}